// Round 10
// baseline (443.507 us; speedup 1.0000x reference)
//
#include <hip/hip_runtime.h>
#include <cstddef>
#include <cstdint>

#define NG   100
#define NPG  1000
#define NN   (NG * NPG)       // 100000 nodes
#define NE   (NN * 16)        // 1600000 edges
#define EPG  (NE / NG)        // 16000 edges per graph (edges are graph-local)
#define CSRL 24000            // CSR dwords/graph cap (sum vr ~= 20400 +- 200)
#define MINREC 20             // min padded records per node (5 chunks)
#define FIN  64
#define HID  128
#define RD   64
#define SLOPE 0.01f
#define EPSV  1e-5f
#define NSTRIP 500            // nodes per GEMM/phi block (2 strips per graph)
#define GSN   40              // nodes per gather block (25 strips per graph)

using short8 = __attribute__((ext_vector_type(8))) short;   // 8 bf16 = 4 VGPRs
using f32x4  = __attribute__((ext_vector_type(4))) float;
typedef unsigned short u16;

__device__ __forceinline__ float leaky(float x) { return x >= 0.f ? x : SLOPE * x; }

// fp32 -> bf16 (round-to-nearest-even), bit pattern
__device__ __forceinline__ u16 f2bf(float f) {
  union { float f; unsigned u; } v; v.f = f;
  return (u16)((v.u + 0x7fffu + ((v.u >> 16) & 1u)) >> 16);
}
__device__ __forceinline__ float bf2f(u16 u) {
  union { unsigned u; float f; } v; v.u = ((unsigned)u) << 16;
  return v.f;
}

// XCD-affinity swizzle: block->XCD heuristic is blockIdx%8; pin graph g to
// XCD g%8 so producer/consumer blocks of one graph share an L2.
__device__ __forceinline__ bool swz(int b, int per_g, int& g, int& part) {
  const int xcd = b & 7;
  const int slot = b >> 3;
  g = xcd + 8 * (slot / per_g);
  part = slot % per_g;
  return g < NG;
}

// ---------------------------------------------------------------------------
// Front dispatch (1024 threads/block, grid EXACTLY 256 = 1 block/CU), R8 form
// (R9 half-split build was neutral-to-worse: doubled edge reads, no win):
//   blocks 0..207  : swz(b,2) -> (graph g, role):
//     role0 = CSR build ENTIRELY IN LDS (R6: random 4-B global scatter stores
//             were the cost; R4: packed layout beats fixed-slot). Histogram +
//             scan; scatter into a 96 KB LDS csr image; one coalesced dwordx4
//             copy-out. Pads pre-zeroed by bulk LDS memset. out_isqrt folded
//             into the bf16 edge weight.
//     role1 = GEMM1 (row scale commuted into csr weights).
//   blocks 208..255: weight transposes (48*1024 = 3*HID*HID exactly) + zero
//                    the stats/pool accumulator region (25600 float4).
// ---------------------------------------------------------------------------
struct BldSh {
  unsigned csrl[CSRL];   // 96 KB LDS csr image (16B-aligned at offset 0)
  int hin[NPG];          // 4 KB
  int hout[NPG];         // 4 KB (folded to rsqrt floats in place)
  int cur[NPG];          // 4 KB
  int wtot[16];
  int total;
};
struct GemSh { u16 Xl[64 * FIN]; u16 W[HID * FIN]; };
union FrontSh { BldSh b; GemSh g; };   // ~108 KB

__global__ __launch_bounds__(1024) void front_k(
    const float* __restrict__ X0, const float* __restrict__ ew,
    const int* __restrict__ src, const int* __restrict__ dst,
    const float* __restrict__ W1, const float* __restrict__ W2f,
    const float* __restrict__ R1f, const float* __restrict__ R2f,
    u16* __restrict__ Wt2, u16* __restrict__ Rt1, u16* __restrict__ Rt2,
    int* __restrict__ cin_, int* __restrict__ offs,
    unsigned* __restrict__ csr, u16* __restrict__ bufA,
    float* __restrict__ zeroreg) {
  __shared__ FrontSh u;
  const int b = blockIdx.x;
  const int t = threadIdx.x;
  if (b >= 208) {
    // ---- weight transposes + accumulator zeroing ----
    const int idx = (b - 208) * 1024 + t;            // 0..49151
    {
      const int m = idx >> 14, r = idx & 16383;
      const int n = r >> 7, k = r & 127;
      const float* s = (m == 0) ? W2f : (m == 1) ? R1f : R2f;
      u16* d = (m == 0) ? Wt2 : (m == 1) ? Rt1 : Rt2;
      d[r] = f2bf(s[k * HID + n]);
    }
    if (idx < (8 * NG * HID) / 4)                    // stats+pools zero (25600)
      ((float4*)zeroreg)[idx] = make_float4(0.f, 0.f, 0.f, 0.f);
    return;
  }
  int g, part;
  if (!swz(b, 2, g, part)) return;
  const int lane = t & 63, wave = t >> 6;
  const int nb = g * NPG, eb = g * EPG;

  if (part == 0) {
    // ============== CSR build in LDS (packed segments) ==============
    {
      const uint4 z4 = {0u, 0u, 0u, 0u};
      uint4* c4 = (uint4*)u.b.csrl;
#pragma unroll
      for (int i = 0; i < CSRL / 4 / 1024 + 1; ++i) {
        const int j = t + i * 1024;
        if (j < CSRL / 4) c4[j] = z4;
      }
    }
    if (t < NPG) { u.b.hin[t] = 0; u.b.hout[t] = 0; }
    __syncthreads();
    for (int e = t; e < EPG; e += 4096) {
      int s4[4], d4[4];
#pragma unroll
      for (int k = 0; k < 4; ++k) {
        const int ee = e + k * 1024;
        if (ee < EPG) { s4[k] = src[eb + ee]; d4[k] = dst[eb + ee]; }
        else d4[k] = -1;
      }
#pragma unroll
      for (int k = 0; k < 4; ++k)
        if (d4[k] >= 0) {
          atomicAdd(&u.b.hout[s4[k] - nb], 1);
          atomicAdd(&u.b.hin[d4[k] - nb], 1);
        }
    }
    __syncthreads();
    int v[4], vr[4];
    int loc = 0;
#pragma unroll
    for (int k = 0; k < 4; ++k) {
      const int idx = t * 4 + k;
      v[k] = (idx < NPG) ? u.b.hin[idx] : 0;
      const int c4 = (v[k] + 3) & ~3;
      vr[k] = (idx < NPG) ? ((c4 > MINREC) ? c4 : MINREC) : 0;
      loc += vr[k];
    }
    int incl = loc;
#pragma unroll
    for (int d = 1; d < 64; d <<= 1) {
      const int x = __shfl_up(incl, d);
      if (lane >= d) incl += x;
    }
    if (lane == 63) u.b.wtot[wave] = incl;
    if (t < NPG) cin_[nb + t] = u.b.hin[t];
    __syncthreads();
    // fold: hout -> rsqrt(max(deg,1)) as float bits, in place
    float* houtf = (float*)u.b.hout;
    if (t < NPG) {
      const int c = u.b.hout[t];
      houtf[t] = rsqrtf((float)(c > 0 ? c : 1));
    }
    int wexc = 0;
    for (int i = 0; i < wave; ++i) wexc += u.b.wtot[i];
    int run = wexc + (incl - loc);                   // LOCAL dword offset
#pragma unroll
    for (int k = 0; k < 4; ++k) {
      const int idx = t * 4 + k;
      if (idx < NPG) {
        offs[nb + idx] = g * CSRL + run;             // global offset for gather
        u.b.cur[idx] = run;                          // local cursor
        run += vr[k];
        if (idx == NPG - 1) u.b.total = run;
      }
    }
    __syncthreads();
    // scatter into the LDS csr image (pads already zero)
    for (int e = t; e < EPG; e += 4096) {
      int s4[4], d4[4];
      float w4[4];
#pragma unroll
      for (int k = 0; k < 4; ++k) {
        const int ee = e + k * 1024;
        if (ee < EPG) { s4[k] = src[eb + ee]; d4[k] = dst[eb + ee]; w4[k] = ew[eb + ee]; }
        else d4[k] = -1;
      }
#pragma unroll
      for (int k = 0; k < 4; ++k)
        if (d4[k] >= 0) {
          const int sl = s4[k] - nb;
          const int pos = atomicAdd(&u.b.cur[d4[k] - nb], 1);
          if (pos < CSRL)   // >50-sigma safety guard
            u.b.csrl[pos] = ((unsigned)sl << 16) | (unsigned)f2bf(w4[k] * houtf[sl]);
        }
    }
    __syncthreads();
    // coalesced copy-out (dwordx4)
    {
      const int tot4 = (u.b.total + 3) >> 2;
      const uint4* s4p = (const uint4*)u.b.csrl;
      uint4* d4p = (uint4*)(csr + (size_t)g * CSRL);
      for (int i = t; i < tot4; i += 1024) d4p[i] = s4p[i];
    }
  } else {
    // ================= GEMM1: bufA = bf16(X @ W1), no row scale =============
    const int l15 = lane & 15, quad = lane >> 4;
    const int rg = wave >> 2, cg = wave & 3;
    // stage W1 transposed+swizzled straight from f32 (no pre-pass dependency)
    {
      const int n = t & 127, ko = t >> 7;            // ko: k-octet 0..7
      short8 w8;
#pragma unroll
      for (int j = 0; j < 8; ++j) w8[j] = (short)f2bf(W1[(ko * 8 + j) * HID + n]);
      *(short8*)&u.g.W[n * FIN + ((ko ^ (n & 7)) << 3)] = w8;
    }
    const int kq = t & 15, srow = t >> 4;            // srow 0..63
    float4 xpre = (srow < NPG)
        ? *(const float4*)(X0 + (size_t)(nb + srow) * FIN + kq * 4)
        : make_float4(0.f, 0.f, 0.f, 0.f);
    for (int pass = 0; pass < 16; ++pass) {
      __syncthreads();
      {
        ushort4 uu = make_ushort4(f2bf(xpre.x), f2bf(xpre.y), f2bf(xpre.z), f2bf(xpre.w));
        const int cc = kq >> 1, half = kq & 1;
        *(ushort4*)&u.g.Xl[srow * FIN + (((cc ^ (srow & 7)) << 3) | (half << 2))] = uu;
      }
      __syncthreads();
      if (pass < 15) {
        const int rowi = (pass + 1) * 64 + srow;
        xpre = (rowi < NPG)
            ? *(const float4*)(X0 + (size_t)(nb + rowi) * FIN + kq * 4)
            : make_float4(0.f, 0.f, 0.f, 0.f);
      }
      short8 a[2];
      const int arow = rg * 16 + l15;
#pragma unroll
      for (int kt = 0; kt < 2; ++kt)
        a[kt] = *(const short8*)&u.g.Xl[arow * FIN + (((kt * 4 + quad) ^ (l15 & 7)) << 3)];
      int rows[4];
#pragma unroll
      for (int r = 0; r < 4; ++r) rows[r] = pass * 64 + rg * 16 + quad * 4 + r;
#pragma unroll
      for (int q2 = 0; q2 < 2; ++q2) {
        const int ct = cg * 2 + q2;
        f32x4 acc = {0.f, 0.f, 0.f, 0.f};
        const int brow = ct * 16 + l15;
#pragma unroll
        for (int kt = 0; kt < 2; ++kt) {
          const short8 bb = *(const short8*)&u.g.W[brow * FIN + (((kt * 4 + quad) ^ (l15 & 7)) << 3)];
          acc = __builtin_amdgcn_mfma_f32_16x16x32_bf16(a[kt], bb, acc, 0, 0, 0);
        }
        const int n2 = ct * 16 + l15;
#pragma unroll
        for (int r = 0; r < 4; ++r)
          if (rows[r] < NPG)
            bufA[(size_t)(nb + rows[r]) * HID + n2] = f2bf(acc[r]);
      }
    }
  }
}

// inline GraphNorm affine from raw stats
__device__ __forceinline__ void norm_affine(const float* sx, const float* sq,
                                            const float* alpha, const float* gamma,
                                            const float* beta, int g, int c8,
                                            float* Av, float* Bv) {
  const float inv = 1.0f / NPG;
#pragma unroll
  for (int j = 0; j < 8; ++j) {
    const int f = c8 * 8 + j;
    const float mean = sx[g * HID + f] * inv;
    const float ex2 = sq[g * HID + f] * inv;
    const float am = alpha[f] * mean;
    const float var = fmaxf(ex2 - 2.0f * am * mean + am * am, 0.0f);
    const float A = gamma[f] * rsqrtf(var + EPSV);
    Av[j] = A;
    Bv[j] = beta[f] - A * am;
  }
}

// ---------------------------------------------------------------------------
// Gather, PAIR-SPLIT form: records processed two-at-a-time — lanes 0-31 read
// record r's row, lanes 32-63 read record r+1's row, each lane loading uint2
// (8 B = 4 bf16 features). One load instruction covers TWO records (VMEM
// instrs per chunk 5 -> 3, same cache lines). Even/odd-record partials merge
// with one shfl_xor(32) per node; lanes 0-31 write the uint2 result and own
// the float4 stats reduction. Record words stay SGPR (R5 scalarization).
// ---------------------------------------------------------------------------
__global__ __launch_bounds__(256) void gather_k(const u16* __restrict__ H,
                                                const unsigned* __restrict__ csr,
                                                const int* __restrict__ offs,
                                                const int* __restrict__ cin_,
                                                u16* __restrict__ AGG,
                                                float* __restrict__ sx,
                                                float* __restrict__ sq) {
  __shared__ float redx[4][HID];
  __shared__ float redq[4][HID];
  const int wave = threadIdx.x >> 6;
  const int lane = threadIdx.x & 63;
  const int l32 = lane & 31;
  const bool lo32 = lane < 32;
  int g, part;
  if (!swz(blockIdx.x, 25, g, part)) return;
  const int nb = g * NPG;
  const int base = nb + part * GSN;
  const u16* __restrict__ Hg = H + (size_t)nb * HID;

  float sxv[4] = {0.f, 0.f, 0.f, 0.f};
  float sqv[4] = {0.f, 0.f, 0.f, 0.f};
  for (int it = 0; it < 3; ++it) {            // node groups: 4, 4, 2
    const int nc = (it < 2) ? 4 : 2;
    int nn[4], cnt[4], c4p[4];
    float isq[4];
    const uint4* p[4];
#pragma unroll
    for (int c = 0; c < 4; ++c) {
      const int j = it * 4 + c;
      const int node = base + wave + ((j < 10) ? j : 0) * 4;
      nn[c] = node;
      const int nu = __builtin_amdgcn_readfirstlane(node);
      const int off = __builtin_amdgcn_readfirstlane(offs[nu]);
      cnt[c] = (c < nc) ? __builtin_amdgcn_readfirstlane(cin_[nu]) : 0;
      const int cr = (cnt[c] + 3) & ~3;
      c4p[c] = ((cr > MINREC) ? cr : MINREC) >> 2;  // padded chunk count >= 5
      isq[c] = rsqrtf(fmaxf((float)cnt[c], 1.0f));
      p[c] = (const uint4*)__builtin_assume_aligned(csr + off, 16);
    }
    float acc[4][4];
#pragma unroll
    for (int c = 0; c < 4; ++c)
#pragma unroll
      for (int j = 0; j < 4; ++j) acc[c][j] = 0.f;
#pragma unroll
    for (int t = 0; t < 5; ++t) {             // fixed: all chains have >=5 chunks
      unsigned rs[4][4];
#pragma unroll
      for (int c = 0; c < 4; ++c)
        if (c < nc) {
          const uint4 rv = p[c][t];
          rs[c][0] = __builtin_amdgcn_readfirstlane(rv.x);
          rs[c][1] = __builtin_amdgcn_readfirstlane(rv.y);
          rs[c][2] = __builtin_amdgcn_readfirstlane(rv.z);
          rs[c][3] = __builtin_amdgcn_readfirstlane(rv.w);
        }
      uint2 uA[4], uB[4];
#pragma unroll
      for (int c = 0; c < 4; ++c)
        if (c < nc) {
          const int rowA = (int)((lo32 ? rs[c][0] : rs[c][1]) >> 16);
          const int rowB = (int)((lo32 ? rs[c][2] : rs[c][3]) >> 16);
          uA[c] = *(const uint2*)(Hg + (size_t)rowA * HID + l32 * 4);
          uB[c] = *(const uint2*)(Hg + (size_t)rowB * HID + l32 * 4);
        }
#pragma unroll
      for (int c = 0; c < 4; ++c)
        if (c < nc) {
          const float w0 = bf2f((u16)(rs[c][0] & 0xffffu));
          const float w1 = bf2f((u16)(rs[c][1] & 0xffffu));
          const float w2 = bf2f((u16)(rs[c][2] & 0xffffu));
          const float w3 = bf2f((u16)(rs[c][3] & 0xffffu));
          const float wA = lo32 ? w0 : w1;
          const float wB = lo32 ? w2 : w3;
          acc[c][0] = fmaf(wA, __uint_as_float(uA[c].x << 16), acc[c][0]);
          acc[c][1] = fmaf(wA, __uint_as_float(uA[c].x & 0xffff0000u), acc[c][1]);
          acc[c][2] = fmaf(wA, __uint_as_float(uA[c].y << 16), acc[c][2]);
          acc[c][3] = fmaf(wA, __uint_as_float(uA[c].y & 0xffff0000u), acc[c][3]);
          acc[c][0] = fmaf(wB, __uint_as_float(uB[c].x << 16), acc[c][0]);
          acc[c][1] = fmaf(wB, __uint_as_float(uB[c].x & 0xffff0000u), acc[c][1]);
          acc[c][2] = fmaf(wB, __uint_as_float(uB[c].y << 16), acc[c][2]);
          acc[c][3] = fmaf(wB, __uint_as_float(uB[c].y & 0xffff0000u), acc[c][3]);
        }
    }
#pragma unroll
    for (int c = 0; c < 4; ++c) {             // rare drains (cnt > 20)
      for (int t = 5; t < c4p[c]; ++t) {
        const uint4 rv = p[c][t];
        unsigned rsd[4];
        rsd[0] = __builtin_amdgcn_readfirstlane(rv.x);
        rsd[1] = __builtin_amdgcn_readfirstlane(rv.y);
        rsd[2] = __builtin_amdgcn_readfirstlane(rv.z);
        rsd[3] = __builtin_amdgcn_readfirstlane(rv.w);
        const int rowA = (int)((lo32 ? rsd[0] : rsd[1]) >> 16);
        const int rowB = (int)((lo32 ? rsd[2] : rsd[3]) >> 16);
        const uint2 dA = *(const uint2*)(Hg + (size_t)rowA * HID + l32 * 4);
        const uint2 dB = *(const uint2*)(Hg + (size_t)rowB * HID + l32 * 4);
        const float w0 = bf2f((u16)(rsd[0] & 0xffffu));
        const float w1 = bf2f((u16)(rsd[1] & 0xffffu));
        const float w2 = bf2f((u16)(rsd[2] & 0xffffu));
        const float w3 = bf2f((u16)(rsd[3] & 0xffffu));
        const float wA = lo32 ? w0 : w1;
        const float wB = lo32 ? w2 : w3;
        acc[c][0] = fmaf(wA, __uint_as_float(dA.x << 16), acc[c][0]);
        acc[c][1] = fmaf(wA, __uint_as_float(dA.x & 0xffff0000u), acc[c][1]);
        acc[c][2] = fmaf(wA, __uint_as_float(dA.y << 16), acc[c][2]);
        acc[c][3] = fmaf(wA, __uint_as_float(dA.y & 0xffff0000u), acc[c][3]);
        acc[c][0] = fmaf(wB, __uint_as_float(dB.x << 16), acc[c][0]);
        acc[c][1] = fmaf(wB, __uint_as_float(dB.x & 0xffff0000u), acc[c][1]);
        acc[c][2] = fmaf(wB, __uint_as_float(dB.y << 16), acc[c][2]);
        acc[c][3] = fmaf(wB, __uint_as_float(dB.y & 0xffff0000u), acc[c][3]);
      }
    }
#pragma unroll
    for (int c = 0; c < 4; ++c)
      if (c < nc) {
        float f0 = acc[c][0] + __shfl_xor(acc[c][0], 32);
        float f1 = acc[c][1] + __shfl_xor(acc[c][1], 32);
        float f2 = acc[c][2] + __shfl_xor(acc[c][2], 32);
        float f3 = acc[c][3] + __shfl_xor(acc[c][3], 32);
        const float rx0 = f0 * isq[c], rx1 = f1 * isq[c];
        const float rx2 = f2 * isq[c], rx3 = f3 * isq[c];
        if (lo32) {
          uint2 ov;
          ov.x = (unsigned)f2bf(rx0) | ((unsigned)f2bf(rx1) << 16);
          ov.y = (unsigned)f2bf(rx2) | ((unsigned)f2bf(rx3) << 16);
          *(uint2*)(AGG + (size_t)nn[c] * HID + l32 * 4) = ov;
          sxv[0] += rx0; sxv[1] += rx1; sxv[2] += rx2; sxv[3] += rx3;
          sqv[0] += rx0 * rx0; sqv[1] += rx1 * rx1;
          sqv[2] += rx2 * rx2; sqv[3] += rx3 * rx3;
        }
      }
  }
  if (lo32) {
    float4 vx = make_float4(sxv[0], sxv[1], sxv[2], sxv[3]);
    float4 vq = make_float4(sqv[0], sqv[1], sqv[2], sqv[3]);
    ((float4*)redx[wave])[l32] = vx;
    ((float4*)redq[wave])[l32] = vq;
  }
  __syncthreads();
  const int tid = threadIdx.x;
  if (tid < HID) {
    unsafeAtomicAdd(&sx[g * HID + tid],
                    redx[0][tid] + redx[1][tid] + redx[2][tid] + redx[3][tid]);
  } else {
    const int t = tid - HID;
    unsafeAtomicAdd(&sq[g * HID + t],
                    redq[0][t] + redq[1][t] + redq[2][t] + redq[3][t]);
  }
}

// ---------------------------------------------------------------------------
// Fused layer epilogue, 512-thread form (R8 proven): norm+leaky from stats,
// then BOTH next-layer GEMM (W2 -> Y) and readout phi+pool (R1 -> ps/hs) off
// the same A-fragments, weights LDS-staged (R6 lesson). 8 waves, 128-row
// passes. NO device-scope fences (R3 lesson).
// ---------------------------------------------------------------------------
struct RedT { float red[32][HID]; float hred[32][HID]; };   // 32 KB
union ShT { u16 Xl[128 * HID]; RedT r; };                   // 32 KB

template <bool DO_GEMM>
__global__ __launch_bounds__(512) void phigemm_k(const u16* __restrict__ Xb,
                                                 u16* __restrict__ Y,
                                                 const u16* __restrict__ Wt,
                                                 const u16* __restrict__ Rt,
                                                 const float* __restrict__ sx,
                                                 const float* __restrict__ sq,
                                                 const float* __restrict__ alpha,
                                                 const float* __restrict__ gamma,
                                                 const float* __restrict__ beta,
                                                 const float* __restrict__ b1,
                                                 float* __restrict__ phi_sum,
                                                 float* __restrict__ h_sum) {
  __shared__ ShT sh;                    // 32 KB (Xl, then red/hred)
  __shared__ u16 Rl[HID * HID];         // 32 KB readout phi weight
  __shared__ u16 Wl[DO_GEMM ? HID * HID : 8];  // 32 KB conv weight (gemm variant)
  const int tid = threadIdx.x;
  const int wave = tid >> 6, lane = tid & 63, l15 = lane & 15, quad = lane >> 4;
  int g, part;
  if (!swz(blockIdx.x, 2, g, part)) return;
  const int base = g * NPG + part * NSTRIP;
  const int c8 = tid & 15;
  const int srow = tid >> 4;            // 0..31

  for (int i = tid; i < HID * (HID / 8); i += 512) {
    const int n = i >> 4, c = i & 15;
    const short8 r2 = *(const short8*)(Rt + n * HID + c * 8);
    *(short8*)&Rl[n * HID + ((c ^ (n & 15)) << 3)] = r2;
    if (DO_GEMM) {
      const short8 w = *(const short8*)(Wt + n * HID + c * 8);
      *(short8*)&Wl[n * HID + ((c ^ (n & 15)) << 3)] = w;
    }
  }
  float Av[8], Bv[8];
  norm_affine(sx, sq, alpha, gamma, beta, g, c8, Av, Bv);
  float bcol[8];
#pragma unroll
  for (int ct = 0; ct < 8; ++ct) bcol[ct] = b1[ct * 16 + l15];

  float pooled[8] = {0.f, 0.f, 0.f, 0.f, 0.f, 0.f, 0.f, 0.f};
  float hp[8] = {0.f, 0.f, 0.f, 0.f, 0.f, 0.f, 0.f, 0.f};
  const short8 z8 = {0, 0, 0, 0, 0, 0, 0, 0};
  short8 xpre[4];
#pragma unroll
  for (int it = 0; it < 4; ++it) {
    const int rowi = srow + it * 32;
    xpre[it] = (rowi < NSTRIP) ? *(const short8*)(Xb + (size_t)(base + rowi) * HID + c8 * 8) : z8;
  }
  for (int pass = 0; pass < 4; ++pass) {       // 4 passes x 128 rows = 512 >= 500
    __syncthreads();
#pragma unroll
    for (int it = 0; it < 4; ++it) {
      const int r = srow + it * 32;
      const int rowi = pass * 128 + r;
      short8 o = z8;
      if (rowi < NSTRIP) {
#pragma unroll
        for (int j = 0; j < 8; ++j) {
          const float xn = leaky(fmaf(Av[j], bf2f((u16)xpre[it][j]), Bv[j]));
          hp[j] += xn;
          o[j] = (short)f2bf(xn);
        }
      }
      *(short8*)&sh.Xl[r * HID + ((c8 ^ (r & 15)) << 3)] = o;
    }
    __syncthreads();
    if (pass < 3) {
#pragma unroll
      for (int it = 0; it < 4; ++it) {
        const int rowi = (pass + 1) * 128 + srow + it * 32;
        xpre[it] = (rowi < NSTRIP) ? *(const short8*)(Xb + (size_t)(base + rowi) * HID + c8 * 8) : z8;
      }
    }
    short8 a[4];
    const int arow = wave * 16 + l15;          // 0..127 across 8 waves
#pragma unroll
    for (int kt = 0; kt < 4; ++kt)
      a[kt] = *(const short8*)&sh.Xl[arow * HID + (((kt * 4 + quad) ^ l15) << 3)];
    int rows[4];
#pragma unroll
    for (int r = 0; r < 4; ++r) rows[r] = pass * 128 + wave * 16 + quad * 4 + r;
#pragma unroll
    for (int ct = 0; ct < 8; ++ct) {
      const int brow = ct * 16 + l15;
      if (DO_GEMM) {
        f32x4 accW = {0.f, 0.f, 0.f, 0.f};
#pragma unroll
        for (int kt = 0; kt < 4; ++kt) {
          const short8 bb = *(const short8*)&Wl[brow * HID + (((kt * 4 + quad) ^ l15) << 3)];
          accW = __builtin_amdgcn_mfma_f32_16x16x32_bf16(a[kt], bb, accW, 0, 0, 0);
        }
#pragma unroll
        for (int r = 0; r < 4; ++r)
          if (rows[r] < NSTRIP)
            Y[(size_t)(base + rows[r]) * HID + ct * 16 + l15] = f2bf(accW[r]);
      }
      f32x4 accR = {0.f, 0.f, 0.f, 0.f};
#pragma unroll
      for (int kt = 0; kt < 4; ++kt) {
        const short8 bb = *(const short8*)&Rl[brow * HID + (((kt * 4 + quad) ^ l15) << 3)];
        accR = __builtin_amdgcn_mfma_f32_16x16x32_bf16(a[kt], bb, accR, 0, 0, 0);
      }
#pragma unroll
      for (int r = 0; r < 4; ++r)
        if (rows[r] < NSTRIP) pooled[ct] += leaky(accR[r] + bcol[ct]);
    }
  }
  __syncthreads();   // all Xl reads done -> safe to overwrite with red/hred
  const int qi = wave * 4 + quad;              // 0..31
#pragma unroll
  for (int ct = 0; ct < 8; ++ct) sh.r.red[qi][ct * 16 + l15] = pooled[ct];
#pragma unroll
  for (int j = 0; j < 8; ++j) sh.r.hred[tid >> 4][(tid & 15) * 8 + j] = hp[j];
  __syncthreads();
  if (tid < HID) {
    float s = 0.f;
#pragma unroll
    for (int q = 0; q < 32; ++q) s += sh.r.red[q][tid];
    unsafeAtomicAdd(&phi_sum[g * HID + tid], s);
  } else if (tid < 2 * HID) {
    const int t = tid - HID;
    float s = 0.f;
#pragma unroll
    for (int rr = 0; rr < 32; ++rr) s += sh.r.hred[rr][t];
    unsafeAtomicAdd(&h_sum[g * HID + t], s);
  }
}

// ---------------------------------------------------------------------------
// Readout part 2, both layers in one dispatch (grid 200).
// ---------------------------------------------------------------------------
__global__ __launch_bounds__(64) void fin_k(const float* __restrict__ ps1,
                                            const float* __restrict__ hs1,
                                            const float* __restrict__ ps2,
                                            const float* __restrict__ hs2,
                                            const float* __restrict__ r1w2,
                                            const float* __restrict__ r1b2,
                                            const float* __restrict__ r2w2,
                                            const float* __restrict__ r2b2,
                                            float* __restrict__ out) {
  const int gb = blockIdx.x;
  const bool L2 = gb >= NG;
  const int g = L2 ? gb - NG : gb;
  const float* ps = L2 ? ps2 : ps1;
  const float* hs = L2 ? hs2 : hs1;
  const float* w2 = L2 ? r2w2 : r1w2;
  const float* b2 = L2 ? r2b2 : r1b2;
  const int roff = L2 ? 192 : 0;
  const int moff = L2 ? 256 : 64;
  const int j = threadIdx.x;  // 0..63
  float acc = b2[j];
#pragma unroll 8
  for (int k = 0; k < HID; ++k)
    acc += (ps[g * HID + k] * (1.0f / NPG)) * w2[k * RD + j];
  out[g * 384 + roff + j] = leaky(leaky(acc));
  out[g * 384 + moff + j] = leaky(hs[g * HID + j] * (1.0f / NPG));
  out[g * 384 + moff + 64 + j] = leaky(hs[g * HID + 64 + j] * (1.0f / NPG));
}

// ---------------------------------------------------------------------------
extern "C" void kernel_launch(void* const* d_in, const int* in_sizes, int n_in,
                              void* d_out, int out_size, void* d_ws, size_t ws_size,
                              hipStream_t stream) {
  const float* node_feats = (const float*)d_in[0];
  const float* ew   = (const float*)d_in[1];
  const float* W1   = (const float*)d_in[2];
  const float* W2   = (const float*)d_in[3];
  const float* g1a  = (const float*)d_in[4];
  const float* g1g  = (const float*)d_in[5];
  const float* g1b  = (const float*)d_in[6];
  const float* g2a  = (const float*)d_in[7];
  const float* g2g  = (const float*)d_in[8];
  const float* g2b  = (const float*)d_in[9];
  const float* r1w1 = (const float*)d_in[10];
  const float* r1b1 = (const float*)d_in[11];
  const float* r1w2 = (const float*)d_in[12];
  const float* r1b2 = (const float*)d_in[13];
  const float* r2w1 = (const float*)d_in[14];
  const float* r2b1 = (const float*)d_in[15];
  const float* r2w2 = (const float*)d_in[16];
  const float* r2b2 = (const float*)d_in[17];
  const int* src = (const int*)d_in[18];
  const int* dst = (const int*)d_in[19];
  float* out = (float*)d_out;

  // workspace layout (zeroed region first: pools + stats, 8*NG*HID f32)
  char* wsb = (char*)d_ws;
  float* ps1     = (float*)wsb;                       // zeroed by front_k aux
  float* hs1     = ps1 + NG * HID;
  float* ps2     = hs1 + NG * HID;
  float* hs2     = ps2 + NG * HID;
  float* sx1     = hs2 + NG * HID;
  float* sq1     = sx1 + NG * HID;
  float* sx2     = sq1 + NG * HID;
  float* sq2     = sx2 + NG * HID;
  int*   cin     = (int*)(sq2 + NG * HID);            // NN (direct store)
  int*   offs    = cin + NN;                          // NN (direct store)
  unsigned* csr  = (unsigned*)(offs + NN);            // NG*CSRL dwords (9.6 MB)
  u16*   Wt2     = (u16*)(csr + (size_t)NG * CSRL);   // 128*128 bf16 x3
  u16*   Rt1     = Wt2 + HID * HID;
  u16*   Rt2     = Rt1 + HID * HID;
  u16*   bufA    = Rt2 + HID * HID;                   // NN*HID bf16
  u16*   bufB    = bufA + (size_t)NN * HID;           // NN*HID bf16

  const int gemm_grid = 8 * 2 * 13;     // XCD-swizzled, 2 strips/graph
  const int gather_grid = 8 * 25 * 13;  // XCD-swizzled, 25 strips/graph

  // dispatch 1: build || gemm1 || weight-transpose || accumulator-zero
  front_k<<<256, 1024, 0, stream>>>(node_feats, ew, src, dst,
                                    W1, W2, r1w1, r2w1,
                                    Wt2, Rt1, Rt2,
                                    cin, offs, csr, bufA, ps1);

  // ---- layer 1 ----
  gather_k<<<gather_grid, 256, 0, stream>>>(bufA, csr, offs, cin, bufB, sx1, sq1);
  phigemm_k<true><<<gemm_grid, 512, 0, stream>>>(bufB, bufA, Wt2, Rt1,
                                                 sx1, sq1, g1a, g1g, g1b,
                                                 r1b1, ps1, hs1);

  // ---- layer 2 ----
  gather_k<<<gather_grid, 256, 0, stream>>>(bufA, csr, offs, cin, bufB, sx2, sq2);
  phigemm_k<false><<<gemm_grid, 512, 0, stream>>>(bufB, nullptr, nullptr, Rt2,
                                                  sx2, sq2, g2a, g2g, g2b,
                                                  r2b1, ps2, hs2);

  // readout part 2, both layers
  fin_k<<<2 * NG, 64, 0, stream>>>(ps1, hs1, ps2, hs2, r1w2, r1b2, r2w2, r2b2, out);
}

// Round 11
// 257.200 us; speedup vs baseline: 1.7244x; 1.7244x over previous
//
#include <hip/hip_runtime.h>
#include <cstddef>
#include <cstdint>

#define NG   100
#define NPG  1000
#define NN   (NG * NPG)       // 100000 nodes
#define NE   (NN * 16)        // 1600000 edges
#define EPG  (NE / NG)        // 16000 edges per graph (edges are graph-local)
#define CSRL 24000            // CSR dwords/graph cap (sum vr ~= 20400 +- 200)
#define MINREC 20             // min padded records per node (5 chunks)
#define FIN  64
#define HID  128
#define RD   64
#define SLOPE 0.01f
#define EPSV  1e-5f
#define NSTRIP 500            // nodes per GEMM/phi block (2 strips per graph)
#define GSN   40              // nodes per gather block (25 strips per graph)

using short8 = __attribute__((ext_vector_type(8))) short;   // 8 bf16 = 4 VGPRs
using f32x4  = __attribute__((ext_vector_type(4))) float;
typedef unsigned short u16;

__device__ __forceinline__ float leaky(float x) { return x >= 0.f ? x : SLOPE * x; }

// fp32 -> bf16 (round-to-nearest-even), bit pattern
__device__ __forceinline__ u16 f2bf(float f) {
  union { float f; unsigned u; } v; v.f = f;
  return (u16)((v.u + 0x7fffu + ((v.u >> 16) & 1u)) >> 16);
}
__device__ __forceinline__ float bf2f(u16 u) {
  union { unsigned u; float f; } v; v.u = ((unsigned)u) << 16;
  return v.f;
}

// XCD-affinity swizzle: block->XCD heuristic is blockIdx%8; pin graph g to
// XCD g%8 so producer/consumer blocks of one graph share an L2.
__device__ __forceinline__ bool swz(int b, int per_g, int& g, int& part) {
  const int xcd = b & 7;
  const int slot = b >> 3;
  g = xcd + 8 * (slot / per_g);
  part = slot % per_g;
  return g < NG;
}

// ---------------------------------------------------------------------------
// Front dispatch (1024 threads/block, grid EXACTLY 256 = 1 block/CU):
//   blocks 0..207  : swz(b,2) -> (graph g, role):
//     role0 = CSR build ENTIRELY IN LDS (R6: random 4-B global scatter stores
//             were the cost; R4: packed layout beats fixed-slot). Histogram +
//             scan; scatter into a 96 KB LDS csr image; one coalesced dwordx4
//             copy-out. Pads pre-zeroed by bulk LDS memset. out_isqrt folded
//             into the bf16 edge weight.
//     role1 = GEMM1 (row scale commuted into csr weights).
//   blocks 208..255: weight transposes (48*1024 = 3*HID*HID exactly) + zero
//                    the stats/pool accumulator region (25600 float4).
// ---------------------------------------------------------------------------
struct BldSh {
  unsigned csrl[CSRL];   // 96 KB LDS csr image (16B-aligned at offset 0)
  int hin[NPG];          // 4 KB
  int hout[NPG];         // 4 KB (folded to rsqrt floats in place)
  int cur[NPG];          // 4 KB
  int wtot[16];
  int total;
};
struct GemSh { u16 Xl[64 * FIN]; u16 W[HID * FIN]; };
union FrontSh { BldSh b; GemSh g; };   // ~108 KB

__global__ __launch_bounds__(1024) void front_k(
    const float* __restrict__ X0, const float* __restrict__ ew,
    const int* __restrict__ src, const int* __restrict__ dst,
    const float* __restrict__ W1, const float* __restrict__ W2f,
    const float* __restrict__ R1f, const float* __restrict__ R2f,
    u16* __restrict__ Wt2, u16* __restrict__ Rt1, u16* __restrict__ Rt2,
    int* __restrict__ cin_, int* __restrict__ offs,
    unsigned* __restrict__ csr, u16* __restrict__ bufA,
    float* __restrict__ zeroreg) {
  __shared__ FrontSh u;
  const int b = blockIdx.x;
  const int t = threadIdx.x;
  if (b >= 208) {
    // ---- weight transposes + accumulator zeroing ----
    const int idx = (b - 208) * 1024 + t;            // 0..49151
    {
      const int m = idx >> 14, r = idx & 16383;
      const int n = r >> 7, k = r & 127;
      const float* s = (m == 0) ? W2f : (m == 1) ? R1f : R2f;
      u16* d = (m == 0) ? Wt2 : (m == 1) ? Rt1 : Rt2;
      d[r] = f2bf(s[k * HID + n]);
    }
    if (idx < (8 * NG * HID) / 4)                    // stats+pools zero (25600)
      ((float4*)zeroreg)[idx] = make_float4(0.f, 0.f, 0.f, 0.f);
    return;
  }
  int g, part;
  if (!swz(b, 2, g, part)) return;
  const int lane = t & 63, wave = t >> 6;
  const int nb = g * NPG, eb = g * EPG;

  if (part == 0) {
    // ============== CSR build in LDS (packed segments) ==============
    {
      const uint4 z4 = {0u, 0u, 0u, 0u};
      uint4* c4 = (uint4*)u.b.csrl;
#pragma unroll
      for (int i = 0; i < CSRL / 4 / 1024 + 1; ++i) {
        const int j = t + i * 1024;
        if (j < CSRL / 4) c4[j] = z4;
      }
    }
    if (t < NPG) { u.b.hin[t] = 0; u.b.hout[t] = 0; }
    __syncthreads();
    for (int e = t; e < EPG; e += 4096) {
      int s4[4], d4[4];
#pragma unroll
      for (int k = 0; k < 4; ++k) {
        const int ee = e + k * 1024;
        if (ee < EPG) { s4[k] = src[eb + ee]; d4[k] = dst[eb + ee]; }
        else d4[k] = -1;
      }
#pragma unroll
      for (int k = 0; k < 4; ++k)
        if (d4[k] >= 0) {
          atomicAdd(&u.b.hout[s4[k] - nb], 1);
          atomicAdd(&u.b.hin[d4[k] - nb], 1);
        }
    }
    __syncthreads();
    int v[4], vr[4];
    int loc = 0;
#pragma unroll
    for (int k = 0; k < 4; ++k) {
      const int idx = t * 4 + k;
      v[k] = (idx < NPG) ? u.b.hin[idx] : 0;
      const int c4 = (v[k] + 3) & ~3;
      vr[k] = (idx < NPG) ? ((c4 > MINREC) ? c4 : MINREC) : 0;
      loc += vr[k];
    }
    int incl = loc;
#pragma unroll
    for (int d = 1; d < 64; d <<= 1) {
      const int x = __shfl_up(incl, d);
      if (lane >= d) incl += x;
    }
    if (lane == 63) u.b.wtot[wave] = incl;
    if (t < NPG) cin_[nb + t] = u.b.hin[t];
    __syncthreads();
    // fold: hout -> rsqrt(max(deg,1)) as float bits, in place
    float* houtf = (float*)u.b.hout;
    if (t < NPG) {
      const int c = u.b.hout[t];
      houtf[t] = rsqrtf((float)(c > 0 ? c : 1));
    }
    int wexc = 0;
    for (int i = 0; i < wave; ++i) wexc += u.b.wtot[i];
    int run = wexc + (incl - loc);                   // LOCAL dword offset
#pragma unroll
    for (int k = 0; k < 4; ++k) {
      const int idx = t * 4 + k;
      if (idx < NPG) {
        offs[nb + idx] = g * CSRL + run;             // global offset for gather
        u.b.cur[idx] = run;                          // local cursor
        run += vr[k];
        if (idx == NPG - 1) u.b.total = run;
      }
    }
    __syncthreads();
    // scatter into the LDS csr image (pads already zero)
    for (int e = t; e < EPG; e += 4096) {
      int s4[4], d4[4];
      float w4[4];
#pragma unroll
      for (int k = 0; k < 4; ++k) {
        const int ee = e + k * 1024;
        if (ee < EPG) { s4[k] = src[eb + ee]; d4[k] = dst[eb + ee]; w4[k] = ew[eb + ee]; }
        else d4[k] = -1;
      }
#pragma unroll
      for (int k = 0; k < 4; ++k)
        if (d4[k] >= 0) {
          const int sl = s4[k] - nb;
          const int pos = atomicAdd(&u.b.cur[d4[k] - nb], 1);
          if (pos < CSRL)   // >50-sigma safety guard
            u.b.csrl[pos] = ((unsigned)sl << 16) | (unsigned)f2bf(w4[k] * houtf[sl]);
        }
    }
    __syncthreads();
    // coalesced copy-out (dwordx4)
    {
      const int tot4 = (u.b.total + 3) >> 2;
      const uint4* s4p = (const uint4*)u.b.csrl;
      uint4* d4p = (uint4*)(csr + (size_t)g * CSRL);
      for (int i = t; i < tot4; i += 1024) d4p[i] = s4p[i];
    }
  } else {
    // ================= GEMM1: bufA = bf16(X @ W1), no row scale =============
    const int l15 = lane & 15, quad = lane >> 4;
    const int rg = wave >> 2, cg = wave & 3;
    // stage W1 transposed+swizzled straight from f32 (no pre-pass dependency)
    {
      const int n = t & 127, ko = t >> 7;            // ko: k-octet 0..7
      short8 w8;
#pragma unroll
      for (int j = 0; j < 8; ++j) w8[j] = (short)f2bf(W1[(ko * 8 + j) * HID + n]);
      *(short8*)&u.g.W[n * FIN + ((ko ^ (n & 7)) << 3)] = w8;
    }
    const int kq = t & 15, srow = t >> 4;            // srow 0..63
    float4 xpre = (srow < NPG)
        ? *(const float4*)(X0 + (size_t)(nb + srow) * FIN + kq * 4)
        : make_float4(0.f, 0.f, 0.f, 0.f);
    for (int pass = 0; pass < 16; ++pass) {
      __syncthreads();
      {
        ushort4 uu = make_ushort4(f2bf(xpre.x), f2bf(xpre.y), f2bf(xpre.z), f2bf(xpre.w));
        const int cc = kq >> 1, half = kq & 1;
        *(ushort4*)&u.g.Xl[srow * FIN + (((cc ^ (srow & 7)) << 3) | (half << 2))] = uu;
      }
      __syncthreads();
      if (pass < 15) {
        const int rowi = (pass + 1) * 64 + srow;
        xpre = (rowi < NPG)
            ? *(const float4*)(X0 + (size_t)(nb + rowi) * FIN + kq * 4)
            : make_float4(0.f, 0.f, 0.f, 0.f);
      }
      short8 a[2];
      const int arow = rg * 16 + l15;
#pragma unroll
      for (int kt = 0; kt < 2; ++kt)
        a[kt] = *(const short8*)&u.g.Xl[arow * FIN + (((kt * 4 + quad) ^ (l15 & 7)) << 3)];
      int rows[4];
#pragma unroll
      for (int r = 0; r < 4; ++r) rows[r] = pass * 64 + rg * 16 + quad * 4 + r;
#pragma unroll
      for (int q2 = 0; q2 < 2; ++q2) {
        const int ct = cg * 2 + q2;
        f32x4 acc = {0.f, 0.f, 0.f, 0.f};
        const int brow = ct * 16 + l15;
#pragma unroll
        for (int kt = 0; kt < 2; ++kt) {
          const short8 bb = *(const short8*)&u.g.W[brow * FIN + (((kt * 4 + quad) ^ (l15 & 7)) << 3)];
          acc = __builtin_amdgcn_mfma_f32_16x16x32_bf16(a[kt], bb, acc, 0, 0, 0);
        }
        const int n2 = ct * 16 + l15;
#pragma unroll
        for (int r = 0; r < 4; ++r)
          if (rows[r] < NPG)
            bufA[(size_t)(nb + rows[r]) * HID + n2] = f2bf(acc[r]);
      }
    }
  }
}

// inline GraphNorm affine from raw stats
__device__ __forceinline__ void norm_affine(const float* sx, const float* sq,
                                            const float* alpha, const float* gamma,
                                            const float* beta, int g, int c8,
                                            float* Av, float* Bv) {
  const float inv = 1.0f / NPG;
#pragma unroll
  for (int j = 0; j < 8; ++j) {
    const int f = c8 * 8 + j;
    const float mean = sx[g * HID + f] * inv;
    const float ex2 = sq[g * HID + f] * inv;
    const float am = alpha[f] * mean;
    const float var = fmaxf(ex2 - 2.0f * am * mean + am * am, 0.0f);
    const float A = gamma[f] * rsqrtf(var + EPSV);
    Av[j] = A;
    Bv[j] = beta[f] - A * am;
  }
}

// ---------------------------------------------------------------------------
// Gather: scalar-pipe CSR (R5/R8 proven form: record words readfirstlane'd to
// SGPRs, full-wave saddr row loads), 4 chains/wave over PADDED packed
// segments, fixed 5-chunk interleave + rare drains. R10 lesson: pair-split
// with __shfl_xor(32) merge = 4x REGRESSION (ds_bpermute LDS conflicts +
// de-scalarized row bases). csr weights carry out_isqrt[src].
// ---------------------------------------------------------------------------
__global__ __launch_bounds__(256) void gather_k(const u16* __restrict__ H,
                                                const unsigned* __restrict__ csr,
                                                const int* __restrict__ offs,
                                                const int* __restrict__ cin_,
                                                u16* __restrict__ AGG,
                                                float* __restrict__ sx,
                                                float* __restrict__ sq) {
  __shared__ float redx[4][HID];
  __shared__ float redq[4][HID];
  const int wave = threadIdx.x >> 6;
  const int lane = threadIdx.x & 63;
  int g, part;
  if (!swz(blockIdx.x, 25, g, part)) return;
  const int nb = g * NPG;
  const int base = nb + part * GSN;
  const int loff = lane * 2;
  const u16* __restrict__ Hg = H + (size_t)nb * HID;

  float sxa = 0.f, sxb = 0.f, sqa = 0.f, sqb = 0.f;
  for (int it = 0; it < 3; ++it) {            // node groups: 4, 4, 2
    const int nc = (it < 2) ? 4 : 2;
    int nn[4], cnt[4], c4p[4];
    float isq[4];
    const uint4* p[4];
#pragma unroll
    for (int c = 0; c < 4; ++c) {
      const int j = it * 4 + c;
      const int node = base + wave + ((j < 10) ? j : 0) * 4;
      nn[c] = node;
      const int nu = __builtin_amdgcn_readfirstlane(node);
      const int off = __builtin_amdgcn_readfirstlane(offs[nu]);
      cnt[c] = (c < nc) ? __builtin_amdgcn_readfirstlane(cin_[nu]) : 0;
      const int cr = (cnt[c] + 3) & ~3;
      c4p[c] = ((cr > MINREC) ? cr : MINREC) >> 2;  // padded chunk count >= 5
      isq[c] = rsqrtf(fmaxf((float)cnt[c], 1.0f));
      p[c] = (const uint4*)__builtin_assume_aligned(csr + off, 16);
    }
    float ax[4] = {0.f, 0.f, 0.f, 0.f};
    float ay[4] = {0.f, 0.f, 0.f, 0.f};
#pragma unroll
    for (int t = 0; t < 5; ++t) {             // fixed: all chains have >=5 chunks
      unsigned rs[4][4];
#pragma unroll
      for (int c = 0; c < 4; ++c)
        if (c < nc) {
          const uint4 rv = p[c][t];
          rs[c][0] = __builtin_amdgcn_readfirstlane(rv.x);
          rs[c][1] = __builtin_amdgcn_readfirstlane(rv.y);
          rs[c][2] = __builtin_amdgcn_readfirstlane(rv.z);
          rs[c][3] = __builtin_amdgcn_readfirstlane(rv.w);
        }
      unsigned uu[4][4];
#pragma unroll
      for (int c = 0; c < 4; ++c)
        if (c < nc) {
#pragma unroll
          for (int q = 0; q < 4; ++q)
            uu[c][q] = ((const unsigned*)(Hg + (size_t)(rs[c][q] >> 16) * HID))[lane];
        }
#pragma unroll
      for (int c = 0; c < 4; ++c)
        if (c < nc) {
#pragma unroll
          for (int q = 0; q < 4; ++q) {
            const float w = bf2f((u16)(rs[c][q] & 0xffffu));
            ax[c] = fmaf(w, __uint_as_float(uu[c][q] << 16), ax[c]);
            ay[c] = fmaf(w, __uint_as_float(uu[c][q] & 0xffff0000u), ay[c]);
          }
        }
    }
#pragma unroll
    for (int c = 0; c < 4; ++c) {             // rare drains (cnt > 20)
      for (int t = 5; t < c4p[c]; ++t) {
        const uint4 rv = p[c][t];
        unsigned rsd[4];
        rsd[0] = __builtin_amdgcn_readfirstlane(rv.x);
        rsd[1] = __builtin_amdgcn_readfirstlane(rv.y);
        rsd[2] = __builtin_amdgcn_readfirstlane(rv.z);
        rsd[3] = __builtin_amdgcn_readfirstlane(rv.w);
#pragma unroll
        for (int q = 0; q < 4; ++q) {
          const unsigned uq = ((const unsigned*)(Hg + (size_t)(rsd[q] >> 16) * HID))[lane];
          const float w = bf2f((u16)(rsd[q] & 0xffffu));
          ax[c] = fmaf(w, __uint_as_float(uq << 16), ax[c]);
          ay[c] = fmaf(w, __uint_as_float(uq & 0xffff0000u), ay[c]);
        }
      }
    }
#pragma unroll
    for (int c = 0; c < 4; ++c)
      if (c < nc) {
        const float rx = ax[c] * isq[c];
        const float ry = ay[c] * isq[c];
        *(unsigned*)(AGG + (size_t)nn[c] * HID + loff) =
            (unsigned)f2bf(rx) | ((unsigned)f2bf(ry) << 16);
        sxa += rx; sxb += ry;
        sqa += rx * rx; sqb += ry * ry;
      }
  }
  redx[wave][loff] = sxa; redx[wave][loff + 1] = sxb;
  redq[wave][loff] = sqa; redq[wave][loff + 1] = sqb;
  __syncthreads();
  const int tid = threadIdx.x;
  if (tid < HID) {
    unsafeAtomicAdd(&sx[g * HID + tid],
                    redx[0][tid] + redx[1][tid] + redx[2][tid] + redx[3][tid]);
  } else {
    const int t = tid - HID;
    unsafeAtomicAdd(&sq[g * HID + t],
                    redq[0][t] + redq[1][t] + redq[2][t] + redq[3][t]);
  }
}

// ---------------------------------------------------------------------------
// Fused layer epilogue, 512-thread form (R8 proven): norm+leaky from stats,
// then BOTH next-layer GEMM (W2 -> Y) and readout phi+pool (R1 -> ps/hs) off
// the same A-fragments, weights LDS-staged (R6 lesson). 8 waves, 128-row
// passes. NO device-scope fences (R3 lesson).
// ---------------------------------------------------------------------------
struct RedT { float red[32][HID]; float hred[32][HID]; };   // 32 KB
union ShT { u16 Xl[128 * HID]; RedT r; };                   // 32 KB

template <bool DO_GEMM>
__global__ __launch_bounds__(512) void phigemm_k(const u16* __restrict__ Xb,
                                                 u16* __restrict__ Y,
                                                 const u16* __restrict__ Wt,
                                                 const u16* __restrict__ Rt,
                                                 const float* __restrict__ sx,
                                                 const float* __restrict__ sq,
                                                 const float* __restrict__ alpha,
                                                 const float* __restrict__ gamma,
                                                 const float* __restrict__ beta,
                                                 const float* __restrict__ b1,
                                                 float* __restrict__ phi_sum,
                                                 float* __restrict__ h_sum) {
  __shared__ ShT sh;                    // 32 KB (Xl, then red/hred)
  __shared__ u16 Rl[HID * HID];         // 32 KB readout phi weight
  __shared__ u16 Wl[DO_GEMM ? HID * HID : 8];  // 32 KB conv weight (gemm variant)
  const int tid = threadIdx.x;
  const int wave = tid >> 6, lane = tid & 63, l15 = lane & 15, quad = lane >> 4;
  int g, part;
  if (!swz(blockIdx.x, 2, g, part)) return;
  const int base = g * NPG + part * NSTRIP;
  const int c8 = tid & 15;
  const int srow = tid >> 4;            // 0..31

  for (int i = tid; i < HID * (HID / 8); i += 512) {
    const int n = i >> 4, c = i & 15;
    const short8 r2 = *(const short8*)(Rt + n * HID + c * 8);
    *(short8*)&Rl[n * HID + ((c ^ (n & 15)) << 3)] = r2;
    if (DO_GEMM) {
      const short8 w = *(const short8*)(Wt + n * HID + c * 8);
      *(short8*)&Wl[n * HID + ((c ^ (n & 15)) << 3)] = w;
    }
  }
  float Av[8], Bv[8];
  norm_affine(sx, sq, alpha, gamma, beta, g, c8, Av, Bv);
  float bcol[8];
#pragma unroll
  for (int ct = 0; ct < 8; ++ct) bcol[ct] = b1[ct * 16 + l15];

  float pooled[8] = {0.f, 0.f, 0.f, 0.f, 0.f, 0.f, 0.f, 0.f};
  float hp[8] = {0.f, 0.f, 0.f, 0.f, 0.f, 0.f, 0.f, 0.f};
  const short8 z8 = {0, 0, 0, 0, 0, 0, 0, 0};
  short8 xpre[4];
#pragma unroll
  for (int it = 0; it < 4; ++it) {
    const int rowi = srow + it * 32;
    xpre[it] = (rowi < NSTRIP) ? *(const short8*)(Xb + (size_t)(base + rowi) * HID + c8 * 8) : z8;
  }
  for (int pass = 0; pass < 4; ++pass) {       // 4 passes x 128 rows = 512 >= 500
    __syncthreads();
#pragma unroll
    for (int it = 0; it < 4; ++it) {
      const int r = srow + it * 32;
      const int rowi = pass * 128 + r;
      short8 o = z8;
      if (rowi < NSTRIP) {
#pragma unroll
        for (int j = 0; j < 8; ++j) {
          const float xn = leaky(fmaf(Av[j], bf2f((u16)xpre[it][j]), Bv[j]));
          hp[j] += xn;
          o[j] = (short)f2bf(xn);
        }
      }
      *(short8*)&sh.Xl[r * HID + ((c8 ^ (r & 15)) << 3)] = o;
    }
    __syncthreads();
    if (pass < 3) {
#pragma unroll
      for (int it = 0; it < 4; ++it) {
        const int rowi = (pass + 1) * 128 + srow + it * 32;
        xpre[it] = (rowi < NSTRIP) ? *(const short8*)(Xb + (size_t)(base + rowi) * HID + c8 * 8) : z8;
      }
    }
    short8 a[4];
    const int arow = wave * 16 + l15;          // 0..127 across 8 waves
#pragma unroll
    for (int kt = 0; kt < 4; ++kt)
      a[kt] = *(const short8*)&sh.Xl[arow * HID + (((kt * 4 + quad) ^ l15) << 3)];
    int rows[4];
#pragma unroll
    for (int r = 0; r < 4; ++r) rows[r] = pass * 128 + wave * 16 + quad * 4 + r;
#pragma unroll
    for (int ct = 0; ct < 8; ++ct) {
      const int brow = ct * 16 + l15;
      if (DO_GEMM) {
        f32x4 accW = {0.f, 0.f, 0.f, 0.f};
#pragma unroll
        for (int kt = 0; kt < 4; ++kt) {
          const short8 bb = *(const short8*)&Wl[brow * HID + (((kt * 4 + quad) ^ l15) << 3)];
          accW = __builtin_amdgcn_mfma_f32_16x16x32_bf16(a[kt], bb, accW, 0, 0, 0);
        }
#pragma unroll
        for (int r = 0; r < 4; ++r)
          if (rows[r] < NSTRIP)
            Y[(size_t)(base + rows[r]) * HID + ct * 16 + l15] = f2bf(accW[r]);
      }
      f32x4 accR = {0.f, 0.f, 0.f, 0.f};
#pragma unroll
      for (int kt = 0; kt < 4; ++kt) {
        const short8 bb = *(const short8*)&Rl[brow * HID + (((kt * 4 + quad) ^ l15) << 3)];
        accR = __builtin_amdgcn_mfma_f32_16x16x32_bf16(a[kt], bb, accR, 0, 0, 0);
      }
#pragma unroll
      for (int r = 0; r < 4; ++r)
        if (rows[r] < NSTRIP) pooled[ct] += leaky(accR[r] + bcol[ct]);
    }
  }
  __syncthreads();   // all Xl reads done -> safe to overwrite with red/hred
  const int qi = wave * 4 + quad;              // 0..31
#pragma unroll
  for (int ct = 0; ct < 8; ++ct) sh.r.red[qi][ct * 16 + l15] = pooled[ct];
#pragma unroll
  for (int j = 0; j < 8; ++j) sh.r.hred[tid >> 4][(tid & 15) * 8 + j] = hp[j];
  __syncthreads();
  if (tid < HID) {
    float s = 0.f;
#pragma unroll
    for (int q = 0; q < 32; ++q) s += sh.r.red[q][tid];
    unsafeAtomicAdd(&phi_sum[g * HID + tid], s);
  } else if (tid < 2 * HID) {
    const int t = tid - HID;
    float s = 0.f;
#pragma unroll
    for (int rr = 0; rr < 32; ++rr) s += sh.r.hred[rr][t];
    unsafeAtomicAdd(&h_sum[g * HID + t], s);
  }
}

// ---------------------------------------------------------------------------
// Readout part 2, both layers in one dispatch (grid 200).
// ---------------------------------------------------------------------------
__global__ __launch_bounds__(64) void fin_k(const float* __restrict__ ps1,
                                            const float* __restrict__ hs1,
                                            const float* __restrict__ ps2,
                                            const float* __restrict__ hs2,
                                            const float* __restrict__ r1w2,
                                            const float* __restrict__ r1b2,
                                            const float* __restrict__ r2w2,
                                            const float* __restrict__ r2b2,
                                            float* __restrict__ out) {
  const int gb = blockIdx.x;
  const bool L2 = gb >= NG;
  const int g = L2 ? gb - NG : gb;
  const float* ps = L2 ? ps2 : ps1;
  const float* hs = L2 ? hs2 : hs1;
  const float* w2 = L2 ? r2w2 : r1w2;
  const float* b2 = L2 ? r2b2 : r1b2;
  const int roff = L2 ? 192 : 0;
  const int moff = L2 ? 256 : 64;
  const int j = threadIdx.x;  // 0..63
  float acc = b2[j];
#pragma unroll 8
  for (int k = 0; k < HID; ++k)
    acc += (ps[g * HID + k] * (1.0f / NPG)) * w2[k * RD + j];
  out[g * 384 + roff + j] = leaky(leaky(acc));
  out[g * 384 + moff + j] = leaky(hs[g * HID + j] * (1.0f / NPG));
  out[g * 384 + moff + 64 + j] = leaky(hs[g * HID + 64 + j] * (1.0f / NPG));
}

// ---------------------------------------------------------------------------
extern "C" void kernel_launch(void* const* d_in, const int* in_sizes, int n_in,
                              void* d_out, int out_size, void* d_ws, size_t ws_size,
                              hipStream_t stream) {
  const float* node_feats = (const float*)d_in[0];
  const float* ew   = (const float*)d_in[1];
  const float* W1   = (const float*)d_in[2];
  const float* W2   = (const float*)d_in[3];
  const float* g1a  = (const float*)d_in[4];
  const float* g1g  = (const float*)d_in[5];
  const float* g1b  = (const float*)d_in[6];
  const float* g2a  = (const float*)d_in[7];
  const float* g2g  = (const float*)d_in[8];
  const float* g2b  = (const float*)d_in[9];
  const float* r1w1 = (const float*)d_in[10];
  const float* r1b1 = (const float*)d_in[11];
  const float* r1w2 = (const float*)d_in[12];
  const float* r1b2 = (const float*)d_in[13];
  const float* r2w1 = (const float*)d_in[14];
  const float* r2b1 = (const float*)d_in[15];
  const float* r2w2 = (const float*)d_in[16];
  const float* r2b2 = (const float*)d_in[17];
  const int* src = (const int*)d_in[18];
  const int* dst = (const int*)d_in[19];
  float* out = (float*)d_out;

  // workspace layout (zeroed region first: pools + stats, 8*NG*HID f32)
  char* wsb = (char*)d_ws;
  float* ps1     = (float*)wsb;                       // zeroed by front_k aux
  float* hs1     = ps1 + NG * HID;
  float* ps2     = hs1 + NG * HID;
  float* hs2     = ps2 + NG * HID;
  float* sx1     = hs2 + NG * HID;
  float* sq1     = sx1 + NG * HID;
  float* sx2     = sq1 + NG * HID;
  float* sq2     = sx2 + NG * HID;
  int*   cin     = (int*)(sq2 + NG * HID);            // NN (direct store)
  int*   offs    = cin + NN;                          // NN (direct store)
  unsigned* csr  = (unsigned*)(offs + NN);            // NG*CSRL dwords (9.6 MB)
  u16*   Wt2     = (u16*)(csr + (size_t)NG * CSRL);   // 128*128 bf16 x3
  u16*   Rt1     = Wt2 + HID * HID;
  u16*   Rt2     = Rt1 + HID * HID;
  u16*   bufA    = Rt2 + HID * HID;                   // NN*HID bf16
  u16*   bufB    = bufA + (size_t)NN * HID;           // NN*HID bf16

  const int gemm_grid = 8 * 2 * 13;     // XCD-swizzled, 2 strips/graph
  const int gather_grid = 8 * 25 * 13;  // XCD-swizzled, 25 strips/graph

  // dispatch 1: build || gemm1 || weight-transpose || accumulator-zero
  front_k<<<256, 1024, 0, stream>>>(node_feats, ew, src, dst,
                                    W1, W2, r1w1, r2w1,
                                    Wt2, Rt1, Rt2,
                                    cin, offs, csr, bufA, ps1);

  // ---- layer 1 ----
  gather_k<<<gather_grid, 256, 0, stream>>>(bufA, csr, offs, cin, bufB, sx1, sq1);
  phigemm_k<true><<<gemm_grid, 512, 0, stream>>>(bufB, bufA, Wt2, Rt1,
                                                 sx1, sq1, g1a, g1g, g1b,
                                                 r1b1, ps1, hs1);

  // ---- layer 2 ----
  gather_k<<<gather_grid, 256, 0, stream>>>(bufA, csr, offs, cin, bufB, sx2, sq2);
  phigemm_k<false><<<gemm_grid, 512, 0, stream>>>(bufB, nullptr, nullptr, Rt2,
                                                  sx2, sq2, g2a, g2g, g2b,
                                                  r2b1, ps2, hs2);

  // readout part 2, both layers
  fin_k<<<2 * NG, 64, 0, stream>>>(ps1, hs1, ps2, hs2, r1w2, r1b2, r2w2, r2b2, out);
}